// Round 8
// baseline (212.608 us; speedup 1.0000x reference)
//
#include <hip/hip_runtime.h>
#include <hip/hip_bf16.h>
#include <math.h>

#define BB 4
#define LL 8192
#define DD 512
#define HH 8
#define MM (BB*LL)      // 32768
#define NQKV 1536
#define CH 32           // K-chunks for kv partial reduction (Kc = 256)

typedef __attribute__((ext_vector_type(4))) float f32x4;
typedef __attribute__((ext_vector_type(8))) short s16x8;
typedef __attribute__((ext_vector_type(4))) short s16x4;

__device__ __forceinline__ float bf2f(short u) {
  union { unsigned int i; float f; } c;
  c.i = ((unsigned int)(unsigned short)u) << 16;
  return c.f;
}
__device__ __forceinline__ short f2bf(float f) {
  union { float f; unsigned int i; } c; c.f = f;
  unsigned int r = c.i + 0x7FFFu + ((c.i >> 16) & 1u);
  return (short)(r >> 16);
}

__device__ __forceinline__ void gload16(const void* g, void* l) {
  __builtin_amdgcn_global_load_lds(
      (const __attribute__((address_space(1))) void*)(g),
      (__attribute__((address_space(3))) void*)(l), 16, 0, 0);
}

// ---------------- conversion kernels ----------------
__global__ void conv_bf16(const float* __restrict__ in, short* __restrict__ out, int n) {
  int i = (blockIdx.x * blockDim.x + threadIdx.x) * 4;
  if (i < n) {
    float4 v = *reinterpret_cast<const float4*>(in + i);
    s16x4 o;
    o[0] = f2bf(v.x); o[1] = f2bf(v.y); o[2] = f2bf(v.z); o[3] = f2bf(v.w);
    *reinterpret_cast<s16x4*>(out + i) = o;
  }
}

// w[K][N] (row-major) -> wt[N][K] bf16
__global__ void conv_wt(const float* __restrict__ w, short* __restrict__ wt, int K, int N) {
  int idx = blockIdx.x * blockDim.x + threadIdx.x;
  if (idx < K * N) {
    int n = idx / K, k = idx - n * K;
    wt[idx] = f2bf(w[(size_t)k * N + n]);
  }
}

// ---------------- bf16 MFMA GEMM (r6-proven), C = A @ BT^T + bias ----------------
// 256x128 tile, BK=64, 8 waves (4M x 2N), per-wave 64x64 out.  48KB staged LDS,
// 64KB epilogue scratch, m-major XCD chunking (A slice = one XCD's 4MB L2).
// Staging swizzle: row r, 16B-unit u stored at (u ^ (r&7)), pre-swizzled source.
// MODE 0 (qkv): q cols -> phi + row-major q_b[M][512];
//               k cols -> phi + per-head transpose kt[head][dh][8192];
//               v cols -> per-head transpose vt[head][m][8192].
template<int MODE>
__global__ __launch_bounds__(512, 4)
void gemm_bt(const short* __restrict__ A, const short* __restrict__ BT,
             const float* __restrict__ bias, void* __restrict__ Cout,
             short* __restrict__ ktb, short* __restrict__ vtb)
{
  constexpr int KD = 512;
  __shared__ __align__(16) char lds[65536];   // As 32KB | Bs 16KB; epilogue reuses 64KB

  const int tid = threadIdx.x;
  const int wv = tid >> 6, lane = tid & 63;
  const int wm = wv >> 1, wn = wv & 1;        // 4 m-waves x 2 n-waves
  const int fr = lane & 15, fq = lane >> 4;

  // m-major XCD chunking: each XCD owns a contiguous m-stripe
  const int gx = gridDim.x;                   // # m-blocks
  const int gy = gridDim.y;                   // # n-blocks
  const int d = blockIdx.y * gx + blockIdx.x;
  const int nwg = gx * gy;
  const int lin = (d & 7) * (nwg >> 3) + (d >> 3);
  const int m0 = (lin / gy) * 256, n0 = (lin % gy) * 128;

  // staging: rows (tid>>3)+i*64; LDS unit tid&7 holds global unit (tid&7)^(row&7)
  const int srow = tid >> 3;
  const int sunit = (tid & 7) ^ (srow & 7);
  const short* Ag = A  + (size_t)(m0 + srow) * KD + sunit * 8;
  const short* Bg = BT + (size_t)(n0 + srow) * KD + sunit * 8;
  char* ldsw = lds + wv * 1024;               // + lane*16 implicit in gload_lds

  f32x4 acc[4][4] = {};

  for (int t = 0; t < 8; ++t) {
    const int k0 = t * 64;
#pragma unroll
    for (int i = 0; i < 4; ++i)
      gload16(Ag + (size_t)(i * 64) * KD + k0, ldsw + i * 8192);
#pragma unroll
    for (int i = 0; i < 2; ++i)
      gload16(Bg + (size_t)(i * 64) * KD + k0, ldsw + 32768 + i * 8192);
    __syncthreads();
#pragma unroll
    for (int kk = 0; kk < 2; ++kk) {
      s16x8 af[4], bfg[4];
#pragma unroll
      for (int i = 0; i < 4; ++i) {
        const int ra = wm * 64 + i * 16 + fr;
        const int ua = (kk * 4 + fq) ^ (ra & 7);
        af[i] = *(const s16x8*)(lds + ra * 128 + ua * 16);
      }
#pragma unroll
      for (int j = 0; j < 4; ++j) {
        const int rb = wn * 64 + j * 16 + fr;
        const int ub = (kk * 4 + fq) ^ (rb & 7);
        bfg[j] = *(const s16x8*)(lds + 32768 + rb * 128 + ub * 16);
      }
#pragma unroll
      for (int i = 0; i < 4; ++i)
#pragma unroll
        for (int j = 0; j < 4; ++j)
          acc[i][j] = __builtin_amdgcn_mfma_f32_16x16x32_bf16(af[i], bfg[j], acc[i][j], 0, 0, 0);
    }
    __syncthreads();
  }

  // ---- epilogue ----
  if (MODE == 0) {
    if (n0 < 512) {
      // q: phi + row-major bf16 to Cout (q_b), stride 512
      short* scr = (short*)lds;   // 256x128
#pragma unroll
      for (int j = 0; j < 4; ++j) {
        const int col = wn * 64 + j * 16 + fr;
        const float bv = bias[n0 + col];
#pragma unroll
        for (int i = 0; i < 4; ++i) {
          const int row = wm * 64 + i * 16 + fq * 4;
#pragma unroll
          for (int r = 0; r < 4; ++r) {
            float v = acc[i][j][r] + bv;
            v = (v > 0.f) ? (v + 1.f) : __expf(v);   // phi = elu+1
            scr[(row + r) * 128 + col] = f2bf(v);
          }
        }
      }
      __syncthreads();
#pragma unroll
      for (int p = 0; p < 8; ++p) {
        const int off = p * 8192 + tid * 16;          // bytes
        const int row = off >> 8, colb = off & 255;   // 256B per row
        s16x8 v = *(const s16x8*)(lds + off);
        *(s16x8*)((short*)Cout + (size_t)(m0 + row) * 512 + n0 + (colb >> 1)) = v;
      }
    } else {
      // k/v: (phi for k) + per-head transposed write via scr_t[col][l]
      const bool do_phi = (n0 < 1024);
      short* tdst = do_phi ? ktb : vtb;
      const int f0 = n0 - (do_phi ? 512 : 1024);
#pragma unroll
      for (int j = 0; j < 4; ++j) {
        const int col = wn * 64 + j * 16 + fr;
        const float bv = bias[n0 + col];
        const int cx = col & 31;
#pragma unroll
        for (int i = 0; i < 4; ++i) {
          const int l = wm * 64 + i * 16 + fq * 4;
          s16x4 pk;
#pragma unroll
          for (int r = 0; r < 4; ++r) {
            float v = acc[i][j][r] + bv;
            if (do_phi) v = (v > 0.f) ? (v + 1.f) : __expf(v);
            pk[r] = f2bf(v);
          }
          *(s16x4*)(lds + col * 512 + (((l >> 3) ^ cx) * 16) + (l & 7) * 2) = pk;
        }
      }
      __syncthreads();
#pragma unroll
      for (int p = 0; p < 8; ++p) {
        const int g = p * 512 + tid;
        const int col = g >> 5, up = g & 31;
        const int u = up ^ (col & 31);
        s16x8 v = *(const s16x8*)(lds + col * 512 + up * 16);
        const int f = f0 + col;
        const int hb = ((m0 >> 13) << 3) + (f >> 6);
        short* dst = tdst + ((size_t)hb * 64 + (f & 63)) * 8192 + (m0 & 8191) + u * 8;
        *(s16x8*)dst = v;
      }
    }
  }
}

// ---------------- kv partials via MFMA ----------------
__global__ __launch_bounds__(256, 4)
void kv_mfma(const short* __restrict__ kt, const short* __restrict__ vt,
             float* __restrict__ pkv, float* __restrict__ pks)
{
  const int hb = blockIdx.x, c = blockIdx.y;
  const int tid = threadIdx.x, wv = tid >> 6, lane = tid & 63;
  const int fr = lane & 15, fq = lane >> 4;
  const size_t base = (size_t)hb * 64 * 8192;
  const int l0 = c * 256;
  const short* vrow = vt + base + (size_t)fr * 8192 + l0 + fq * 8;
  const short* krow = kt + base + (size_t)(wv * 16 + fr) * 8192 + l0 + fq * 8;

  s16x8 ones;
#pragma unroll
  for (int j = 0; j < 8; ++j) ones[j] = (short)0x3F80;   // bf16 1.0

  f32x4 acc[4] = {};
  f32x4 accd = {};
#pragma unroll
  for (int ks = 0; ks < 8; ++ks) {
    s16x8 bfr = *(const s16x8*)(krow + ks * 32);
    accd = __builtin_amdgcn_mfma_f32_16x16x32_bf16(ones, bfr, accd, 0, 0, 0);
#pragma unroll
    for (int i = 0; i < 4; ++i) {
      s16x8 af = *(const s16x8*)(vrow + (size_t)(i * 16) * 8192 + ks * 32);
      acc[i] = __builtin_amdgcn_mfma_f32_16x16x32_bf16(af, bfr, acc[i], 0, 0, 0);
    }
  }
  float* o = pkv + ((size_t)hb * CH + c) * 4096;
#pragma unroll
  for (int i = 0; i < 4; ++i)
#pragma unroll
    for (int r = 0; r < 4; ++r)
      o[(i * 16 + fq * 4 + r) * 64 + wv * 16 + fr] = acc[i][r];
  if (fq == 0)
    pks[((size_t)hb * CH + c) * 64 + wv * 16 + fr] = accd[0];
}

// reduce partials -> bf16 kv_b [head][m][d], bf16 ksum_b [head][d] (with +1e-6)
__global__ void kv_reduce(const float* __restrict__ pkv, const float* __restrict__ pks,
                          short* __restrict__ kv_b, short* __restrict__ ksum_b)
{
  const int idx = blockIdx.x * 256 + threadIdx.x;   // head*4096 + m*64 + d
  const int head = idx >> 12, md = idx & 4095;
  float s = 0.f;
  for (int i = 0; i < CH; ++i) s += pkv[((size_t)head * CH + i) * 4096 + md];
  kv_b[idx] = f2bf(s);
  if (md < 64) {
    float t = 0.f;
    for (int i = 0; i < CH; ++i) t += pks[((size_t)head * CH + i) * 64 + md];
    ksum_b[head * 64 + md] = f2bf(t + 1e-6f);
  }
}

// ---------------- fused attn + output GEMM ----------------
// Per block: 64 rows (one batch).  Phase A: wave w = head w computes
// attn[64][64] = (Q.kv^T)/(Q.ksum) -> bf16 LDS tile [64][512], unit-swizzled
// (unit ^= row&7).  Phase B: out[64][512] = attn @ wo_t^T + b_out, A-frags from
// LDS (2-way free), B-frags from L2-resident wo_t; fp32 out staged via LDS.
__global__ __launch_bounds__(512, 4)
void attn_out(const short* __restrict__ q_b, const short* __restrict__ kv_b,
              const short* __restrict__ ksum_b, const short* __restrict__ wo_t,
              const float* __restrict__ b_out, float* __restrict__ out)
{
  __shared__ __align__(16) char lds[65536];
  const int tid = threadIdx.x;
  const int wv = tid >> 6, lane = tid & 63;
  const int fr = lane & 15, fq = lane >> 4;
  const int l0 = blockIdx.x * 64;

  // ---- Phase A: head wv, rows l0..l0+63 ----
  {
    const int hb = ((l0 >> 13) << 3) + wv;
    const short* kvp = kv_b + (size_t)hb * 4096;
    const short* ksp = ksum_b + hb * 64;
    const short* qb = q_b + (size_t)l0 * 512 + wv * 64;

    f32x4 accn[4][4] = {};
    f32x4 accd[4] = {};
#pragma unroll
    for (int kk = 0; kk < 2; ++kk) {
      s16x8 bfr[4], bden;
#pragma unroll
      for (int j = 0; j < 4; ++j)
        bfr[j] = *(const s16x8*)(kvp + (j * 16 + fr) * 64 + kk * 32 + fq * 8);
      bden = *(const s16x8*)(ksp + kk * 32 + fq * 8);
#pragma unroll
      for (int i = 0; i < 4; ++i) {
        s16x8 a = *(const s16x8*)(qb + (size_t)(i * 16 + fr) * 512 + kk * 32 + fq * 8);
        accd[i] = __builtin_amdgcn_mfma_f32_16x16x32_bf16(a, bden, accd[i], 0, 0, 0);
#pragma unroll
        for (int j = 0; j < 4; ++j)
          accn[i][j] = __builtin_amdgcn_mfma_f32_16x16x32_bf16(a, bfr[j], accn[i][j], 0, 0, 0);
      }
    }
    // write attn -> LDS tile [64][512] bf16, unit-swizzled
#pragma unroll
    for (int i = 0; i < 4; ++i) {
#pragma unroll
      for (int r = 0; r < 4; ++r) {
        const int row = i * 16 + fq * 4 + r;
        const float dinv = 1.0f / accd[i][r];
#pragma unroll
        for (int j = 0; j < 4; ++j) {
          const int col = wv * 64 + j * 16 + fr;
          *(short*)(lds + row * 1024 + (((col >> 3) ^ (row & 7)) << 4) + ((col & 7) << 1))
              = f2bf(accn[i][j][r] * dinv);
        }
      }
    }
  }
  __syncthreads();

  // ---- Phase B: out = attn @ wo_t^T + b_out ----
  const int wm = wv >> 2, wn = wv & 3;        // 2 m-waves (32 rows) x 4 n-waves (128 cols)
  f32x4 acc[2][8] = {};
  for (int kt = 0; kt < 16; ++kt) {
    s16x8 af[2];
#pragma unroll
    for (int i = 0; i < 2; ++i) {
      const int row = wm * 32 + i * 16 + fr;
      const int u = (kt * 4 + fq) ^ (row & 7);
      af[i] = *(const s16x8*)(lds + row * 1024 + u * 16);
    }
#pragma unroll
    for (int j = 0; j < 8; ++j) {
      const int n = wn * 128 + j * 16 + fr;
      s16x8 bfw = *(const s16x8*)(wo_t + (size_t)n * 512 + kt * 32 + fq * 8);
#pragma unroll
      for (int i = 0; i < 2; ++i)
        acc[i][j] = __builtin_amdgcn_mfma_f32_16x16x32_bf16(af[i], bfw, acc[i][j], 0, 0, 0);
    }
  }
  __syncthreads();

  // epilogue: two 32-row halves through LDS fp32 scratch, coalesced stores
  float* scrf = (float*)lds;
#pragma unroll
  for (int h = 0; h < 2; ++h) {
    if (wm == h) {
#pragma unroll
      for (int j = 0; j < 8; ++j) {
        const int col = wn * 128 + j * 16 + fr;
        const float bv = b_out[col];
#pragma unroll
        for (int i = 0; i < 2; ++i) {
          const int row = i * 16 + fq * 4;
#pragma unroll
          for (int r = 0; r < 4; ++r)
            scrf[(row + r) * 512 + col] = acc[i][j][r] + bv;
        }
      }
    }
    __syncthreads();
#pragma unroll
    for (int p = 0; p < 8; ++p) {
      const int off = p * 8192 + tid * 16;
      const int row = off >> 11, colb = off & 2047;   // 2KB per row (512 fp32)
      float4 v = *(const float4*)(lds + off);
      *(float4*)(out + (size_t)(l0 + h * 32 + row) * 512 + (colb >> 2)) = v;
    }
    __syncthreads();
  }
}

// ---------------- launch ----------------
extern "C" void kernel_launch(void* const* d_in, const int* in_sizes, int n_in,
                              void* d_out, int out_size, void* d_ws, size_t ws_size,
                              hipStream_t stream)
{
  const float* x     = (const float*)d_in[0];
  const float* w_qkv = (const float*)d_in[1];
  const float* b_qkv = (const float*)d_in[2];
  const float* w_out = (const float*)d_in[3];
  const float* b_out = (const float*)d_in[4];

  char* ws = (char*)d_ws;
  size_t off = 0;
  short* x_b   = (short*)(ws + off); off += (size_t)MM * DD * 2;        // 32 MB
  short* wq_t  = (short*)(ws + off); off += (size_t)NQKV * DD * 2;      // 1.5 MB
  short* wo_t  = (short*)(ws + off); off += (size_t)DD * DD * 2;        // 0.5 MB
  short* q_b   = (short*)(ws + off); off += (size_t)MM * DD * 2;        // 32 MB
  short* kt    = (short*)(ws + off); off += (size_t)32 * 64 * LL * 2;   // 32 MB
  short* vt    = (short*)(ws + off); off += (size_t)32 * 64 * LL * 2;   // 32 MB
  float* pkv   = (float*)(ws + off); off += (size_t)32 * CH * 4096 * 4; // 16 MB
  float* pks   = (float*)(ws + off); off += (size_t)32 * CH * 64 * 4;   // 0.25 MB
  short* kv_b  = (short*)(ws + off); off += (size_t)32 * 4096 * 2;      // 0.25 MB
  short* ksum_b= (short*)(ws + off); off += (size_t)32 * 64 * 2;        // 4 KB

  conv_bf16<<<dim3((MM * DD / 4 + 255) / 256), dim3(256), 0, stream>>>(x, x_b, MM * DD);
  conv_wt<<<dim3((DD * NQKV + 255) / 256), dim3(256), 0, stream>>>(w_qkv, wq_t, DD, NQKV);
  conv_wt<<<dim3((DD * DD + 255) / 256), dim3(256), 0, stream>>>(w_out, wo_t, DD, DD);

  // qkv GEMM: q -> q_b (phi), k -> kt (phi, transposed), v -> vt (transposed)
  gemm_bt<0><<<dim3(MM / 256, NQKV / 128), dim3(512), 0, stream>>>(
      x_b, wq_t, b_qkv, (void*)q_b, kt, vt);

  kv_mfma<<<dim3(32, CH), dim3(256), 0, stream>>>(kt, vt, pkv, pks);
  kv_reduce<<<dim3(512), dim3(256), 0, stream>>>(pkv, pks, kv_b, ksum_b);

  // fused attn + output GEMM -> d_out
  attn_out<<<dim3(MM / 64), dim3(512), 0, stream>>>(
      q_b, kv_b, ksum_b, wo_t, b_out, (float*)d_out);
}

// Round 9
// 212.171 us; speedup vs baseline: 1.0021x; 1.0021x over previous
//
#include <hip/hip_runtime.h>
#include <hip/hip_bf16.h>
#include <math.h>

#define BB 4
#define LL 8192
#define DD 512
#define HH 8
#define MM (BB*LL)      // 32768
#define NQKV 1536
#define CH 32           // K-chunks for kv partial reduction (Kc = 256)

typedef __attribute__((ext_vector_type(4))) float f32x4;
typedef __attribute__((ext_vector_type(8))) short s16x8;
typedef __attribute__((ext_vector_type(4))) short s16x4;

__device__ __forceinline__ float bf2f(short u) {
  union { unsigned int i; float f; } c;
  c.i = ((unsigned int)(unsigned short)u) << 16;
  return c.f;
}
__device__ __forceinline__ short f2bf(float f) {
  union { float f; unsigned int i; } c; c.f = f;
  unsigned int r = c.i + 0x7FFFu + ((c.i >> 16) & 1u);
  return (short)(r >> 16);
}

__device__ __forceinline__ void gload16(const void* g, void* l) {
  __builtin_amdgcn_global_load_lds(
      (const __attribute__((address_space(1))) void*)(g),
      (__attribute__((address_space(3))) void*)(l), 16, 0, 0);
}

// ---------------- conversion kernels ----------------
__global__ void conv_bf16(const float* __restrict__ in, short* __restrict__ out, int n) {
  int i = (blockIdx.x * blockDim.x + threadIdx.x) * 4;
  if (i < n) {
    float4 v = *reinterpret_cast<const float4*>(in + i);
    s16x4 o;
    o[0] = f2bf(v.x); o[1] = f2bf(v.y); o[2] = f2bf(v.z); o[3] = f2bf(v.w);
    *reinterpret_cast<s16x4*>(out + i) = o;
  }
}

// w[K][N] (row-major) -> wt[N][K] bf16
__global__ void conv_wt(const float* __restrict__ w, short* __restrict__ wt, int K, int N) {
  int idx = blockIdx.x * blockDim.x + threadIdx.x;
  if (idx < K * N) {
    int n = idx / K, k = idx - n * K;
    wt[idx] = f2bf(w[(size_t)k * N + n]);
  }
}

// ---------------- bf16 MFMA GEMM (r6-proven), C = A @ BT^T + bias ----------------
// 256x128 tile, BK=64, 8 waves (4M x 2N), per-wave 64x64 out.  48KB staged LDS,
// 64KB epilogue scratch, m-major XCD chunking (A slice = one XCD's 4MB L2).
// Staging swizzle: row r, 16B-unit u stored at (u ^ (r&7)), pre-swizzled source.
// MODE 0 (qkv): q cols -> phi + row-major q_b[M][512];
//               k cols -> phi + per-head transpose kt[head][dh][8192];
//               v cols -> per-head transpose vt[head][m][8192].
template<int MODE>
__global__ __launch_bounds__(512, 4)
void gemm_bt(const short* __restrict__ A, const short* __restrict__ BT,
             const float* __restrict__ bias, void* __restrict__ Cout,
             short* __restrict__ ktb, short* __restrict__ vtb)
{
  constexpr int KD = 512;
  __shared__ __align__(16) char lds[65536];   // As 32KB | Bs 16KB; epilogue reuses 64KB

  const int tid = threadIdx.x;
  const int wv = tid >> 6, lane = tid & 63;
  const int wm = wv >> 1, wn = wv & 1;        // 4 m-waves x 2 n-waves
  const int fr = lane & 15, fq = lane >> 4;

  // m-major XCD chunking: each XCD owns a contiguous m-stripe
  const int gx = gridDim.x;                   // # m-blocks
  const int gy = gridDim.y;                   // # n-blocks
  const int d = blockIdx.y * gx + blockIdx.x;
  const int nwg = gx * gy;
  const int lin = (d & 7) * (nwg >> 3) + (d >> 3);
  const int m0 = (lin / gy) * 256, n0 = (lin % gy) * 128;

  // staging: rows (tid>>3)+i*64; LDS unit tid&7 holds global unit (tid&7)^(row&7)
  const int srow = tid >> 3;
  const int sunit = (tid & 7) ^ (srow & 7);
  const short* Ag = A  + (size_t)(m0 + srow) * KD + sunit * 8;
  const short* Bg = BT + (size_t)(n0 + srow) * KD + sunit * 8;
  char* ldsw = lds + wv * 1024;               // + lane*16 implicit in gload_lds

  f32x4 acc[4][4] = {};

  for (int t = 0; t < 8; ++t) {
    const int k0 = t * 64;
#pragma unroll
    for (int i = 0; i < 4; ++i)
      gload16(Ag + (size_t)(i * 64) * KD + k0, ldsw + i * 8192);
#pragma unroll
    for (int i = 0; i < 2; ++i)
      gload16(Bg + (size_t)(i * 64) * KD + k0, ldsw + 32768 + i * 8192);
    __syncthreads();
#pragma unroll
    for (int kk = 0; kk < 2; ++kk) {
      s16x8 af[4], bfg[4];
#pragma unroll
      for (int i = 0; i < 4; ++i) {
        const int ra = wm * 64 + i * 16 + fr;
        const int ua = (kk * 4 + fq) ^ (ra & 7);
        af[i] = *(const s16x8*)(lds + ra * 128 + ua * 16);
      }
#pragma unroll
      for (int j = 0; j < 4; ++j) {
        const int rb = wn * 64 + j * 16 + fr;
        const int ub = (kk * 4 + fq) ^ (rb & 7);
        bfg[j] = *(const s16x8*)(lds + 32768 + rb * 128 + ub * 16);
      }
#pragma unroll
      for (int i = 0; i < 4; ++i)
#pragma unroll
        for (int j = 0; j < 4; ++j)
          acc[i][j] = __builtin_amdgcn_mfma_f32_16x16x32_bf16(af[i], bfg[j], acc[i][j], 0, 0, 0);
    }
    __syncthreads();
  }

  // ---- epilogue ----
  if (MODE == 0) {
    if (n0 < 512) {
      // q: phi + row-major bf16 to Cout (q_b), stride 512
      short* scr = (short*)lds;   // 256x128
#pragma unroll
      for (int j = 0; j < 4; ++j) {
        const int col = wn * 64 + j * 16 + fr;
        const float bv = bias[n0 + col];
#pragma unroll
        for (int i = 0; i < 4; ++i) {
          const int row = wm * 64 + i * 16 + fq * 4;
#pragma unroll
          for (int r = 0; r < 4; ++r) {
            float v = acc[i][j][r] + bv;
            v = (v > 0.f) ? (v + 1.f) : __expf(v);   // phi = elu+1
            scr[(row + r) * 128 + col] = f2bf(v);
          }
        }
      }
      __syncthreads();
#pragma unroll
      for (int p = 0; p < 8; ++p) {
        const int off = p * 8192 + tid * 16;          // bytes
        const int row = off >> 8, colb = off & 255;   // 256B per row
        s16x8 v = *(const s16x8*)(lds + off);
        *(s16x8*)((short*)Cout + (size_t)(m0 + row) * 512 + n0 + (colb >> 1)) = v;
      }
    } else {
      // k/v: (phi for k) + per-head transposed write via scr_t[col][l]
      const bool do_phi = (n0 < 1024);
      short* tdst = do_phi ? ktb : vtb;
      const int f0 = n0 - (do_phi ? 512 : 1024);
#pragma unroll
      for (int j = 0; j < 4; ++j) {
        const int col = wn * 64 + j * 16 + fr;
        const float bv = bias[n0 + col];
        const int cx = col & 31;
#pragma unroll
        for (int i = 0; i < 4; ++i) {
          const int l = wm * 64 + i * 16 + fq * 4;
          s16x4 pk;
#pragma unroll
          for (int r = 0; r < 4; ++r) {
            float v = acc[i][j][r] + bv;
            if (do_phi) v = (v > 0.f) ? (v + 1.f) : __expf(v);
            pk[r] = f2bf(v);
          }
          *(s16x4*)(lds + col * 512 + (((l >> 3) ^ cx) * 16) + (l & 7) * 2) = pk;
        }
      }
      __syncthreads();
#pragma unroll
      for (int p = 0; p < 8; ++p) {
        const int g = p * 512 + tid;
        const int col = g >> 5, up = g & 31;
        const int u = up ^ (col & 31);
        s16x8 v = *(const s16x8*)(lds + col * 512 + up * 16);
        const int f = f0 + col;
        const int hb = ((m0 >> 13) << 3) + (f >> 6);
        short* dst = tdst + ((size_t)hb * 64 + (f & 63)) * 8192 + (m0 & 8191) + u * 8;
        *(s16x8*)dst = v;
      }
    }
  }
}

// ---------------- kv partials via MFMA ----------------
__global__ __launch_bounds__(256, 4)
void kv_mfma(const short* __restrict__ kt, const short* __restrict__ vt,
             float* __restrict__ pkv, float* __restrict__ pks)
{
  const int hb = blockIdx.x, c = blockIdx.y;
  const int tid = threadIdx.x, wv = tid >> 6, lane = tid & 63;
  const int fr = lane & 15, fq = lane >> 4;
  const size_t base = (size_t)hb * 64 * 8192;
  const int l0 = c * 256;
  const short* vrow = vt + base + (size_t)fr * 8192 + l0 + fq * 8;
  const short* krow = kt + base + (size_t)(wv * 16 + fr) * 8192 + l0 + fq * 8;

  s16x8 ones;
#pragma unroll
  for (int j = 0; j < 8; ++j) ones[j] = (short)0x3F80;   // bf16 1.0

  f32x4 acc[4] = {};
  f32x4 accd = {};
#pragma unroll
  for (int ks = 0; ks < 8; ++ks) {
    s16x8 bfr = *(const s16x8*)(krow + ks * 32);
    accd = __builtin_amdgcn_mfma_f32_16x16x32_bf16(ones, bfr, accd, 0, 0, 0);
#pragma unroll
    for (int i = 0; i < 4; ++i) {
      s16x8 af = *(const s16x8*)(vrow + (size_t)(i * 16) * 8192 + ks * 32);
      acc[i] = __builtin_amdgcn_mfma_f32_16x16x32_bf16(af, bfr, acc[i], 0, 0, 0);
    }
  }
  float* o = pkv + ((size_t)hb * CH + c) * 4096;
#pragma unroll
  for (int i = 0; i < 4; ++i)
#pragma unroll
    for (int r = 0; r < 4; ++r)
      o[(i * 16 + fq * 4 + r) * 64 + wv * 16 + fr] = acc[i][r];
  if (fq == 0)
    pks[((size_t)hb * CH + c) * 64 + wv * 16 + fr] = accd[0];
}

// reduce partials -> bf16 kv_b [head][m][d], bf16 ksum_b [head][d] (with +1e-6)
__global__ void kv_reduce(const float* __restrict__ pkv, const float* __restrict__ pks,
                          short* __restrict__ kv_b, short* __restrict__ ksum_b)
{
  const int idx = blockIdx.x * 256 + threadIdx.x;   // head*4096 + m*64 + d
  const int head = idx >> 12, md = idx & 4095;
  float s = 0.f;
  for (int i = 0; i < CH; ++i) s += pkv[((size_t)head * CH + i) * 4096 + md];
  kv_b[idx] = f2bf(s);
  if (md < 64) {
    float t = 0.f;
    for (int i = 0; i < CH; ++i) t += pks[((size_t)head * CH + i) * 64 + md];
    ksum_b[head * 64 + md] = f2bf(t + 1e-6f);
  }
}

// ---------------- fused attn + output GEMM ----------------
// Per block: 64 rows (one batch).  Phase A: wave w = head w computes
// attn[64][64] = (Q.kv^T)/(Q.ksum) -> bf16 LDS tile [64][512], unit-swizzled
// (unit ^= row&7).  Phase B: out[64][512] = attn @ wo_t^T + b_out, A-frags from
// LDS, B-frags from L2-resident wo_t.  Phase B kt loop FULLY UNROLLED with
// loads issued before MFMAs so the compiler can pipeline loads across
// iterations (r8's runtime loop serialized on L2 latency: MfmaUtil 7.8%).
__global__ __launch_bounds__(512, 4)
void attn_out(const short* __restrict__ q_b, const short* __restrict__ kv_b,
              const short* __restrict__ ksum_b, const short* __restrict__ wo_t,
              const float* __restrict__ b_out, float* __restrict__ out)
{
  __shared__ __align__(16) char lds[65536];
  const int tid = threadIdx.x;
  const int wv = tid >> 6, lane = tid & 63;
  const int fr = lane & 15, fq = lane >> 4;
  const int l0 = blockIdx.x * 64;

  // ---- Phase A: head wv, rows l0..l0+63 ----
  {
    const int hb = ((l0 >> 13) << 3) + wv;
    const short* kvp = kv_b + (size_t)hb * 4096;
    const short* ksp = ksum_b + hb * 64;
    const short* qb = q_b + (size_t)l0 * 512 + wv * 64;

    f32x4 accn[4][4] = {};
    f32x4 accd[4] = {};
#pragma unroll
    for (int kk = 0; kk < 2; ++kk) {
      s16x8 bfr[4], bden;
#pragma unroll
      for (int j = 0; j < 4; ++j)
        bfr[j] = *(const s16x8*)(kvp + (j * 16 + fr) * 64 + kk * 32 + fq * 8);
      bden = *(const s16x8*)(ksp + kk * 32 + fq * 8);
#pragma unroll
      for (int i = 0; i < 4; ++i) {
        s16x8 a = *(const s16x8*)(qb + (size_t)(i * 16 + fr) * 512 + kk * 32 + fq * 8);
        accd[i] = __builtin_amdgcn_mfma_f32_16x16x32_bf16(a, bden, accd[i], 0, 0, 0);
#pragma unroll
        for (int j = 0; j < 4; ++j)
          accn[i][j] = __builtin_amdgcn_mfma_f32_16x16x32_bf16(a, bfr[j], accn[i][j], 0, 0, 0);
      }
    }
    // write attn -> LDS tile [64][512] bf16, unit-swizzled
#pragma unroll
    for (int i = 0; i < 4; ++i) {
#pragma unroll
      for (int r = 0; r < 4; ++r) {
        const int row = i * 16 + fq * 4 + r;
        const float dinv = 1.0f / accd[i][r];
#pragma unroll
        for (int j = 0; j < 4; ++j) {
          const int col = wv * 64 + j * 16 + fr;
          *(short*)(lds + row * 1024 + (((col >> 3) ^ (row & 7)) << 4) + ((col & 7) << 1))
              = f2bf(accn[i][j][r] * dinv);
        }
      }
    }
  }
  __syncthreads();

  // ---- Phase B: out = attn @ wo_t^T + b_out ----
  const int wm = wv >> 2, wn = wv & 3;        // 2 m-waves (32 rows) x 4 n-waves (128 cols)
  f32x4 acc[2][8] = {};
  const short* wop = wo_t + (size_t)(wn * 128 + fr) * 512 + fq * 8;
  const int arow0 = wm * 32 + fr;
#pragma unroll
  for (int kt = 0; kt < 16; ++kt) {
    s16x8 bfw[8];
#pragma unroll
    for (int j = 0; j < 8; ++j)
      bfw[j] = *(const s16x8*)(wop + (size_t)(j * 16) * 512 + kt * 32);
    s16x8 af[2];
#pragma unroll
    for (int i = 0; i < 2; ++i) {
      const int row = arow0 + i * 16;
      const int u = (kt * 4 + fq) ^ (row & 7);
      af[i] = *(const s16x8*)(lds + row * 1024 + u * 16);
    }
    __builtin_amdgcn_s_setprio(1);
#pragma unroll
    for (int j = 0; j < 8; ++j)
#pragma unroll
      for (int i = 0; i < 2; ++i)
        acc[i][j] = __builtin_amdgcn_mfma_f32_16x16x32_bf16(af[i], bfw[j], acc[i][j], 0, 0, 0);
    __builtin_amdgcn_s_setprio(0);
  }
  __syncthreads();

  // epilogue: two 32-row halves through LDS fp32 scratch, coalesced stores
  float* scrf = (float*)lds;
#pragma unroll
  for (int h = 0; h < 2; ++h) {
    if (wm == h) {
#pragma unroll
      for (int j = 0; j < 8; ++j) {
        const int col = wn * 128 + j * 16 + fr;
        const float bv = b_out[col];
#pragma unroll
        for (int i = 0; i < 2; ++i) {
          const int row = i * 16 + fq * 4;
#pragma unroll
          for (int r = 0; r < 4; ++r)
            scrf[(row + r) * 512 + col] = acc[i][j][r] + bv;
        }
      }
    }
    __syncthreads();
#pragma unroll
    for (int p = 0; p < 8; ++p) {
      const int off = p * 8192 + tid * 16;
      const int row = off >> 11, colb = off & 2047;   // 2KB per row (512 fp32)
      float4 v = *(const float4*)(lds + off);
      *(float4*)(out + (size_t)(l0 + h * 32 + row) * 512 + (colb >> 2)) = v;
    }
    __syncthreads();
  }
}

// ---------------- launch ----------------
extern "C" void kernel_launch(void* const* d_in, const int* in_sizes, int n_in,
                              void* d_out, int out_size, void* d_ws, size_t ws_size,
                              hipStream_t stream)
{
  const float* x     = (const float*)d_in[0];
  const float* w_qkv = (const float*)d_in[1];
  const float* b_qkv = (const float*)d_in[2];
  const float* w_out = (const float*)d_in[3];
  const float* b_out = (const float*)d_in[4];

  char* ws = (char*)d_ws;
  size_t off = 0;
  short* x_b   = (short*)(ws + off); off += (size_t)MM * DD * 2;        // 32 MB
  short* wq_t  = (short*)(ws + off); off += (size_t)NQKV * DD * 2;      // 1.5 MB
  short* wo_t  = (short*)(ws + off); off += (size_t)DD * DD * 2;        // 0.5 MB
  short* q_b   = (short*)(ws + off); off += (size_t)MM * DD * 2;        // 32 MB
  short* kt    = (short*)(ws + off); off += (size_t)32 * 64 * LL * 2;   // 32 MB
  short* vt    = (short*)(ws + off); off += (size_t)32 * 64 * LL * 2;   // 32 MB
  float* pkv   = (float*)(ws + off); off += (size_t)32 * CH * 4096 * 4; // 16 MB
  float* pks   = (float*)(ws + off); off += (size_t)32 * CH * 64 * 4;   // 0.25 MB
  short* kv_b  = (short*)(ws + off); off += (size_t)32 * 4096 * 2;      // 0.25 MB
  short* ksum_b= (short*)(ws + off); off += (size_t)32 * 64 * 2;        // 4 KB

  conv_bf16<<<dim3((MM * DD / 4 + 255) / 256), dim3(256), 0, stream>>>(x, x_b, MM * DD);
  conv_wt<<<dim3((DD * NQKV + 255) / 256), dim3(256), 0, stream>>>(w_qkv, wq_t, DD, NQKV);
  conv_wt<<<dim3((DD * DD + 255) / 256), dim3(256), 0, stream>>>(w_out, wo_t, DD, DD);

  // qkv GEMM: q -> q_b (phi), k -> kt (phi, transposed), v -> vt (transposed)
  gemm_bt<0><<<dim3(MM / 256, NQKV / 128), dim3(512), 0, stream>>>(
      x_b, wq_t, b_qkv, (void*)q_b, kt, vt);

  kv_mfma<<<dim3(32, CH), dim3(256), 0, stream>>>(kt, vt, pkv, pks);
  kv_reduce<<<dim3(512), dim3(256), 0, stream>>>(pkv, pks, kv_b, ksum_b);

  // fused attn + output GEMM -> d_out
  attn_out<<<dim3(MM / 64), dim3(512), 0, stream>>>(
      q_b, kv_b, ksum_b, wo_t, b_out, (float*)d_out);
}

// Round 11
// 167.937 us; speedup vs baseline: 1.2660x; 1.2634x over previous
//
#include <hip/hip_runtime.h>
#include <hip/hip_bf16.h>
#include <math.h>

#define BB 4
#define LL 8192
#define DD 512
#define HH 8
#define MM (BB*LL)      // 32768
#define NQKV 1536
#define CH 16           // K-chunks for kv partial reduction (Kc = 512)

typedef __attribute__((ext_vector_type(4))) float f32x4;
typedef __attribute__((ext_vector_type(8))) short s16x8;
typedef __attribute__((ext_vector_type(4))) short s16x4;

__device__ __forceinline__ float bf2f(short u) {
  union { unsigned int i; float f; } c;
  c.i = ((unsigned int)(unsigned short)u) << 16;
  return c.f;
}
__device__ __forceinline__ short f2bf(float f) {
  union { float f; unsigned int i; } c; c.f = f;
  unsigned int r = c.i + 0x7FFFu + ((c.i >> 16) & 1u);
  return (short)(r >> 16);
}

__device__ __forceinline__ void gload16(const void* g, void* l) {
  __builtin_amdgcn_global_load_lds(
      (const __attribute__((address_space(1))) void*)(g),
      (__attribute__((address_space(3))) void*)(l), 16, 0, 0);
}

// ---------------- conversion kernels ----------------
__global__ void conv_bf16(const float* __restrict__ in, short* __restrict__ out, int n) {
  int i = (blockIdx.x * blockDim.x + threadIdx.x) * 8;
  if (i < n) {
    float4 v0 = *reinterpret_cast<const float4*>(in + i);
    float4 v1 = *reinterpret_cast<const float4*>(in + i + 4);
    s16x8 o;
    o[0] = f2bf(v0.x); o[1] = f2bf(v0.y); o[2] = f2bf(v0.z); o[3] = f2bf(v0.w);
    o[4] = f2bf(v1.x); o[5] = f2bf(v1.y); o[6] = f2bf(v1.z); o[7] = f2bf(v1.w);
    *reinterpret_cast<s16x8*>(out + i) = o;
  }
}

// w[K][N] (row-major) -> wt[N][K] bf16
__global__ void conv_wt(const float* __restrict__ w, short* __restrict__ wt, int K, int N) {
  int idx = blockIdx.x * blockDim.x + threadIdx.x;
  if (idx < K * N) {
    int n = idx / K, k = idx - n * K;
    wt[idx] = f2bf(w[(size_t)k * N + n]);
  }
}

// ---------------- bf16 MFMA GEMM (r6-proven), C = A @ BT^T + bias ----------------
// 256x128 tile, BK=64, 8 waves (4M x 2N), per-wave 64x64 out.  48KB staged LDS,
// 64KB epilogue scratch, m-major XCD chunking (A slice = one XCD's 4MB L2).
// Staging swizzle: row r, 16B-unit u stored at (u ^ (r&7)), pre-swizzled source.
// MODE 0 (qkv): q cols -> phi + row-major q_b[M][512];
//               k cols -> phi + per-head transpose kt[head][dh][8192];
//               v cols -> per-head transpose vt[head][m][8192].
// MODE 1: bias -> fp32 row-major, stride 512.
template<int MODE>
__global__ __launch_bounds__(512, 4)
void gemm_bt(const short* __restrict__ A, const short* __restrict__ BT,
             const float* __restrict__ bias, void* __restrict__ Cout,
             short* __restrict__ ktb, short* __restrict__ vtb)
{
  constexpr int KD = 512;
  __shared__ __align__(16) char lds[65536];   // As 32KB | Bs 16KB; epilogue reuses 64KB

  const int tid = threadIdx.x;
  const int wv = tid >> 6, lane = tid & 63;
  const int wm = wv >> 1, wn = wv & 1;        // 4 m-waves x 2 n-waves
  const int fr = lane & 15, fq = lane >> 4;

  // m-major XCD chunking: each XCD owns a contiguous m-stripe
  const int gx = gridDim.x;                   // # m-blocks
  const int gy = gridDim.y;                   // # n-blocks
  const int d = blockIdx.y * gx + blockIdx.x;
  const int nwg = gx * gy;
  const int lin = (d & 7) * (nwg >> 3) + (d >> 3);
  const int m0 = (lin / gy) * 256, n0 = (lin % gy) * 128;

  // staging: rows (tid>>3)+i*64; LDS unit tid&7 holds global unit (tid&7)^(row&7)
  const int srow = tid >> 3;
  const int sunit = (tid & 7) ^ (srow & 7);
  const short* Ag = A  + (size_t)(m0 + srow) * KD + sunit * 8;
  const short* Bg = BT + (size_t)(n0 + srow) * KD + sunit * 8;
  char* ldsw = lds + wv * 1024;               // + lane*16 implicit in gload_lds

  f32x4 acc[4][4] = {};

  for (int t = 0; t < 8; ++t) {
    const int k0 = t * 64;
#pragma unroll
    for (int i = 0; i < 4; ++i)
      gload16(Ag + (size_t)(i * 64) * KD + k0, ldsw + i * 8192);
#pragma unroll
    for (int i = 0; i < 2; ++i)
      gload16(Bg + (size_t)(i * 64) * KD + k0, ldsw + 32768 + i * 8192);
    __syncthreads();
#pragma unroll
    for (int kk = 0; kk < 2; ++kk) {
      s16x8 af[4], bfg[4];
#pragma unroll
      for (int i = 0; i < 4; ++i) {
        const int ra = wm * 64 + i * 16 + fr;
        const int ua = (kk * 4 + fq) ^ (ra & 7);
        af[i] = *(const s16x8*)(lds + ra * 128 + ua * 16);
      }
#pragma unroll
      for (int j = 0; j < 4; ++j) {
        const int rb = wn * 64 + j * 16 + fr;
        const int ub = (kk * 4 + fq) ^ (rb & 7);
        bfg[j] = *(const s16x8*)(lds + 32768 + rb * 128 + ub * 16);
      }
#pragma unroll
      for (int i = 0; i < 4; ++i)
#pragma unroll
        for (int j = 0; j < 4; ++j)
          acc[i][j] = __builtin_amdgcn_mfma_f32_16x16x32_bf16(af[i], bfg[j], acc[i][j], 0, 0, 0);
    }
    __syncthreads();
  }

  // ---- epilogue ----
  if (MODE == 0) {
    if (n0 < 512) {
      // q: phi + row-major bf16 to Cout (q_b), stride 512
      short* scr = (short*)lds;   // 256x128
#pragma unroll
      for (int j = 0; j < 4; ++j) {
        const int col = wn * 64 + j * 16 + fr;
        const float bv = bias[n0 + col];
#pragma unroll
        for (int i = 0; i < 4; ++i) {
          const int row = wm * 64 + i * 16 + fq * 4;
#pragma unroll
          for (int r = 0; r < 4; ++r) {
            float v = acc[i][j][r] + bv;
            v = (v > 0.f) ? (v + 1.f) : __expf(v);   // phi = elu+1
            scr[(row + r) * 128 + col] = f2bf(v);
          }
        }
      }
      __syncthreads();
#pragma unroll
      for (int p = 0; p < 8; ++p) {
        const int off = p * 8192 + tid * 16;          // bytes
        const int row = off >> 8, colb = off & 255;   // 256B per row
        s16x8 v = *(const s16x8*)(lds + off);
        *(s16x8*)((short*)Cout + (size_t)(m0 + row) * 512 + n0 + (colb >> 1)) = v;
      }
    } else {
      // k/v: (phi for k) + per-head transposed write via scr_t[col][l]
      const bool do_phi = (n0 < 1024);
      short* tdst = do_phi ? ktb : vtb;
      const int f0 = n0 - (do_phi ? 512 : 1024);
#pragma unroll
      for (int j = 0; j < 4; ++j) {
        const int col = wn * 64 + j * 16 + fr;
        const float bv = bias[n0 + col];
        const int cx = col & 31;
#pragma unroll
        for (int i = 0; i < 4; ++i) {
          const int l = wm * 64 + i * 16 + fq * 4;
          s16x4 pk;
#pragma unroll
          for (int r = 0; r < 4; ++r) {
            float v = acc[i][j][r] + bv;
            if (do_phi) v = (v > 0.f) ? (v + 1.f) : __expf(v);
            pk[r] = f2bf(v);
          }
          *(s16x4*)(lds + col * 512 + (((l >> 3) ^ cx) * 16) + (l & 7) * 2) = pk;
        }
      }
      __syncthreads();
#pragma unroll
      for (int p = 0; p < 8; ++p) {
        const int g = p * 512 + tid;
        const int col = g >> 5, up = g & 31;
        const int u = up ^ (col & 31);
        s16x8 v = *(const s16x8*)(lds + col * 512 + up * 16);
        const int f = f0 + col;
        const int hb = ((m0 >> 13) << 3) + (f >> 6);
        short* dst = tdst + ((size_t)hb * 64 + (f & 63)) * 8192 + (m0 & 8191) + u * 8;
        *(s16x8*)dst = v;
      }
    }
  } else {
    float* scrf = (float*)lds;  // 128x128 fp32 per half
#pragma unroll
    for (int h = 0; h < 2; ++h) {
      __syncthreads();
      if ((wm >> 1) == h) {
#pragma unroll
        for (int j = 0; j < 4; ++j) {
          const int col = wn * 64 + j * 16 + fr;
          const float bv = bias[n0 + col];
#pragma unroll
          for (int i = 0; i < 4; ++i) {
            const int row = (wm & 1) * 64 + i * 16 + fq * 4;
#pragma unroll
            for (int r = 0; r < 4; ++r)
              scrf[(row + r) * 128 + col] = acc[i][j][r] + bv;
          }
        }
      }
      __syncthreads();
#pragma unroll
      for (int p = 0; p < 8; ++p) {
        const int off = p * 8192 + tid * 16;
        const int row = off >> 9, colb = off & 511;   // 512B per row
        float4 v = *(const float4*)(lds + off);
        *(float4*)((float*)Cout + (size_t)(m0 + h * 128 + row) * 512 + n0 + (colb >> 2)) = v;
      }
    }
  }
}

// ---------------- kv partials via MFMA ----------------
// Per block (head hb, chunk c), Kc=512:
//   pkv[hb][c][m][d] = sum_{l in chunk} vt[hb][m][l] * kt[hb][d][l]
//   pks[hb][c][d]    = sum_{l in chunk} kt[hb][d][l]   (ones-A MFMA)
__global__ __launch_bounds__(256, 4)
void kv_mfma(const short* __restrict__ kt, const short* __restrict__ vt,
             float* __restrict__ pkv, float* __restrict__ pks)
{
  const int hb = blockIdx.x, c = blockIdx.y;
  const int tid = threadIdx.x, wv = tid >> 6, lane = tid & 63;
  const int fr = lane & 15, fq = lane >> 4;
  const size_t base = (size_t)hb * 64 * 8192;
  const int l0 = c * 512;
  const short* vrow = vt + base + (size_t)fr * 8192 + l0 + fq * 8;
  const short* krow = kt + base + (size_t)(wv * 16 + fr) * 8192 + l0 + fq * 8;

  s16x8 ones;
#pragma unroll
  for (int j = 0; j < 8; ++j) ones[j] = (short)0x3F80;   // bf16 1.0

  f32x4 acc[4] = {};
  f32x4 accd = {};
#pragma unroll
  for (int ks = 0; ks < 16; ++ks) {
    s16x8 bfr = *(const s16x8*)(krow + ks * 32);
    accd = __builtin_amdgcn_mfma_f32_16x16x32_bf16(ones, bfr, accd, 0, 0, 0);
#pragma unroll
    for (int i = 0; i < 4; ++i) {
      s16x8 af = *(const s16x8*)(vrow + (size_t)(i * 16) * 8192 + ks * 32);
      acc[i] = __builtin_amdgcn_mfma_f32_16x16x32_bf16(af, bfr, acc[i], 0, 0, 0);
    }
  }
  float* o = pkv + ((size_t)hb * CH + c) * 4096;
#pragma unroll
  for (int i = 0; i < 4; ++i)
#pragma unroll
    for (int r = 0; r < 4; ++r)
      o[(i * 16 + fq * 4 + r) * 64 + wv * 16 + fr] = acc[i][r];
  if (fq == 0)
    pks[((size_t)hb * CH + c) * 64 + wv * 16 + fr] = accd[0];
}

// reduce partials -> bf16 kv_b [head][m][d], bf16 ksum_b [head][d] (with +1e-6)
__global__ void kv_reduce(const float* __restrict__ pkv, const float* __restrict__ pks,
                          short* __restrict__ kv_b, short* __restrict__ ksum_b)
{
  const int idx = blockIdx.x * 256 + threadIdx.x;   // head*4096 + m*64 + d
  const int head = idx >> 12, md = idx & 4095;
  float s = 0.f;
  for (int i = 0; i < CH; ++i) s += pkv[((size_t)head * CH + i) * 4096 + md];
  kv_b[idx] = f2bf(s);
  if (md < 64) {
    float t = 0.f;
    for (int i = 0; i < CH; ++i) t += pks[((size_t)head * CH + i) * 64 + md];
    ksum_b[head * 64 + md] = f2bf(t + 1e-6f);
  }
}

// ---------------- attn via MFMA: attn[l][m] = (q_l . kv[m]) / (q_l . ksum) ----------------
__global__ __launch_bounds__(256, 2)
void attn_mfma(const short* __restrict__ q_b, const short* __restrict__ kv_b,
               const short* __restrict__ ksum_b, short* __restrict__ attn)
{
  const int hb = blockIdx.x;     // 0..31 (b*H + h)
  const int tile = blockIdx.y;   // 0..31 (256 rows each)
  const int b = hb >> 3, h = hb & 7;
  const int tid = threadIdx.x, wv = tid >> 6, lane = tid & 63;
  const int fr = lane & 15, fk = (lane >> 4) * 8;

  const short* kvp = kv_b + (size_t)hb * 4096;
  s16x8 bfrag[4][2];
#pragma unroll
  for (int j = 0; j < 4; ++j)
#pragma unroll
    for (int kk = 0; kk < 2; ++kk)
      bfrag[j][kk] = *(const s16x8*)(kvp + (j * 16 + fr) * 64 + kk * 32 + fk);
  s16x8 bden[2];
#pragma unroll
  for (int kk = 0; kk < 2; ++kk)
    bden[kk] = *(const s16x8*)(ksum_b + hb * 64 + kk * 32 + fk);

  const short* qb = q_b + (size_t)b * LL * DD + h * 64;
  const int l0 = tile * 256 + wv * 64;
  f32x4 accn[4][4] = {};
  f32x4 accd[4] = {};
#pragma unroll
  for (int i = 0; i < 4; ++i) {
#pragma unroll
    for (int kk = 0; kk < 2; ++kk) {
      s16x8 a = *(const s16x8*)(qb + (size_t)(l0 + i * 16 + fr) * DD + kk * 32 + fk);
      accd[i] = __builtin_amdgcn_mfma_f32_16x16x32_bf16(a, bden[kk], accd[i], 0, 0, 0);
#pragma unroll
      for (int j = 0; j < 4; ++j)
        accn[i][j] = __builtin_amdgcn_mfma_f32_16x16x32_bf16(a, bfrag[j][kk], accn[i][j], 0, 0, 0);
    }
  }

  short* ob = attn + (size_t)b * LL * DD + h * 64;
  const int fq = lane >> 4;
#pragma unroll
  for (int i = 0; i < 4; ++i) {
#pragma unroll
    for (int r = 0; r < 4; ++r) {
      const int row = l0 + i * 16 + fq * 4 + r;
      const float dinv = 1.0f / accd[i][r];
#pragma unroll
      for (int j = 0; j < 4; ++j) {
        ob[(size_t)row * DD + j * 16 + fr] = f2bf(accn[i][j][r] * dinv);
      }
    }
  }
}

// ---------------- launch ----------------
extern "C" void kernel_launch(void* const* d_in, const int* in_sizes, int n_in,
                              void* d_out, int out_size, void* d_ws, size_t ws_size,
                              hipStream_t stream)
{
  const float* x     = (const float*)d_in[0];
  const float* w_qkv = (const float*)d_in[1];
  const float* b_qkv = (const float*)d_in[2];
  const float* w_out = (const float*)d_in[3];
  const float* b_out = (const float*)d_in[4];

  char* ws = (char*)d_ws;
  size_t off = 0;
  short* x_b   = (short*)(ws + off); off += (size_t)MM * DD * 2;        // 32 MB
  short* wq_t  = (short*)(ws + off); off += (size_t)NQKV * DD * 2;      // 1.5 MB
  short* wo_t  = (short*)(ws + off); off += (size_t)DD * DD * 2;        // 0.5 MB
  short* q_b   = (short*)(ws + off); off += (size_t)MM * DD * 2;        // 32 MB
  short* kt    = (short*)(ws + off); off += (size_t)32 * 64 * LL * 2;   // 32 MB
  short* vt    = (short*)(ws + off); off += (size_t)32 * 64 * LL * 2;   // 32 MB
  short* attn_b= (short*)(ws + off); off += (size_t)MM * DD * 2;        // 32 MB
  float* pkv   = (float*)(ws + off); off += (size_t)32 * CH * 4096 * 4; // 8 MB
  float* pks   = (float*)(ws + off); off += (size_t)32 * CH * 64 * 4;   // 0.13 MB
  short* kv_b  = (short*)(ws + off); off += (size_t)32 * 4096 * 2;      // 0.25 MB
  short* ksum_b= (short*)(ws + off); off += (size_t)32 * 64 * 2;        // 4 KB

  conv_bf16<<<dim3(MM * DD / 8 / 256), dim3(256), 0, stream>>>(x, x_b, MM * DD);
  conv_wt<<<dim3((DD * NQKV + 255) / 256), dim3(256), 0, stream>>>(w_qkv, wq_t, DD, NQKV);
  conv_wt<<<dim3((DD * DD + 255) / 256), dim3(256), 0, stream>>>(w_out, wo_t, DD, DD);

  // qkv GEMM: q -> q_b (phi), k -> kt (phi, transposed), v -> vt (transposed)
  gemm_bt<0><<<dim3(MM / 256, NQKV / 128), dim3(512), 0, stream>>>(
      x_b, wq_t, b_qkv, (void*)q_b, kt, vt);

  kv_mfma<<<dim3(32, CH), dim3(256), 0, stream>>>(kt, vt, pkv, pks);
  kv_reduce<<<dim3(512), dim3(256), 0, stream>>>(pkv, pks, kv_b, ksum_b);

  attn_mfma<<<dim3(32, 32), dim3(256), 0, stream>>>(q_b, kv_b, ksum_b, attn_b);

  // out = attn @ w_out + b_out (fp32)
  gemm_bt<1><<<dim3(MM / 256, DD / 128), dim3(512), 0, stream>>>(
      attn_b, wo_t, b_out, d_out, nullptr, nullptr);
}

// Round 12
// 165.576 us; speedup vs baseline: 1.2840x; 1.0143x over previous
//
#include <hip/hip_runtime.h>
#include <hip/hip_bf16.h>
#include <math.h>

#define BB 4
#define LL 8192
#define DD 512
#define HH 8
#define MM (BB*LL)      // 32768
#define NQKV 1536
#define CH 16           // K-chunks for kv partial reduction (Kc = 512)

typedef __attribute__((ext_vector_type(4))) float f32x4;
typedef __attribute__((ext_vector_type(8))) short s16x8;
typedef __attribute__((ext_vector_type(4))) short s16x4;

__device__ __forceinline__ float bf2f(short u) {
  union { unsigned int i; float f; } c;
  c.i = ((unsigned int)(unsigned short)u) << 16;
  return c.f;
}
__device__ __forceinline__ short f2bf(float f) {
  union { float f; unsigned int i; } c; c.f = f;
  unsigned int r = c.i + 0x7FFFu + ((c.i >> 16) & 1u);
  return (short)(r >> 16);
}

__device__ __forceinline__ void gload16(const void* g, void* l) {
  __builtin_amdgcn_global_load_lds(
      (const __attribute__((address_space(1))) void*)(g),
      (__attribute__((address_space(3))) void*)(l), 16, 0, 0);
}

// ---------------- conversion kernels ----------------
__global__ void conv_bf16(const float* __restrict__ in, short* __restrict__ out, int n) {
  int i = (blockIdx.x * blockDim.x + threadIdx.x) * 8;
  if (i < n) {
    float4 v0 = *reinterpret_cast<const float4*>(in + i);
    float4 v1 = *reinterpret_cast<const float4*>(in + i + 4);
    s16x8 o;
    o[0] = f2bf(v0.x); o[1] = f2bf(v0.y); o[2] = f2bf(v0.z); o[3] = f2bf(v0.w);
    o[4] = f2bf(v1.x); o[5] = f2bf(v1.y); o[6] = f2bf(v1.z); o[7] = f2bf(v1.w);
    *reinterpret_cast<s16x8*>(out + i) = o;
  }
}

// w[K][N] (row-major) -> wt[N][K] bf16
__global__ void conv_wt(const float* __restrict__ w, short* __restrict__ wt, int K, int N) {
  int idx = blockIdx.x * blockDim.x + threadIdx.x;
  if (idx < K * N) {
    int n = idx / K, k = idx - n * K;
    wt[idx] = f2bf(w[(size_t)k * N + n]);
  }
}

// ---------------- bf16 MFMA GEMM (r6-proven), qkv = x @ wqkv^T + bias ----------------
// 256x128 tile, BK=64, 8 waves (4M x 2N), per-wave 64x64 out.  48KB staged LDS,
// 64KB epilogue scratch, m-major XCD chunking (A slice = one XCD's 4MB L2).
// Staging swizzle: row r, 16B-unit u stored at (u ^ (r&7)), pre-swizzled source.
// q cols -> phi + row-major q_b[M][512];
// k cols -> phi + per-head transpose kt[head][dh][8192];
// v cols -> per-head transpose vt[head][m][8192].
__global__ __launch_bounds__(512, 4)
void gemm_bt(const short* __restrict__ A, const short* __restrict__ BT,
             const float* __restrict__ bias, void* __restrict__ Cout,
             short* __restrict__ ktb, short* __restrict__ vtb)
{
  constexpr int KD = 512;
  __shared__ __align__(16) char lds[65536];   // As 32KB | Bs 16KB; epilogue reuses 64KB

  const int tid = threadIdx.x;
  const int wv = tid >> 6, lane = tid & 63;
  const int wm = wv >> 1, wn = wv & 1;        // 4 m-waves x 2 n-waves
  const int fr = lane & 15, fq = lane >> 4;

  // m-major XCD chunking: each XCD owns a contiguous m-stripe
  const int gx = gridDim.x;                   // # m-blocks
  const int gy = gridDim.y;                   // # n-blocks
  const int d = blockIdx.y * gx + blockIdx.x;
  const int nwg = gx * gy;
  const int lin = (d & 7) * (nwg >> 3) + (d >> 3);
  const int m0 = (lin / gy) * 256, n0 = (lin % gy) * 128;

  // staging: rows (tid>>3)+i*64; LDS unit tid&7 holds global unit (tid&7)^(row&7)
  const int srow = tid >> 3;
  const int sunit = (tid & 7) ^ (srow & 7);
  const short* Ag = A  + (size_t)(m0 + srow) * KD + sunit * 8;
  const short* Bg = BT + (size_t)(n0 + srow) * KD + sunit * 8;
  char* ldsw = lds + wv * 1024;               // + lane*16 implicit in gload_lds

  f32x4 acc[4][4] = {};

  for (int t = 0; t < 8; ++t) {
    const int k0 = t * 64;
#pragma unroll
    for (int i = 0; i < 4; ++i)
      gload16(Ag + (size_t)(i * 64) * KD + k0, ldsw + i * 8192);
#pragma unroll
    for (int i = 0; i < 2; ++i)
      gload16(Bg + (size_t)(i * 64) * KD + k0, ldsw + 32768 + i * 8192);
    __syncthreads();
#pragma unroll
    for (int kk = 0; kk < 2; ++kk) {
      s16x8 af[4], bfg[4];
#pragma unroll
      for (int i = 0; i < 4; ++i) {
        const int ra = wm * 64 + i * 16 + fr;
        const int ua = (kk * 4 + fq) ^ (ra & 7);
        af[i] = *(const s16x8*)(lds + ra * 128 + ua * 16);
      }
#pragma unroll
      for (int j = 0; j < 4; ++j) {
        const int rb = wn * 64 + j * 16 + fr;
        const int ub = (kk * 4 + fq) ^ (rb & 7);
        bfg[j] = *(const s16x8*)(lds + 32768 + rb * 128 + ub * 16);
      }
#pragma unroll
      for (int i = 0; i < 4; ++i)
#pragma unroll
        for (int j = 0; j < 4; ++j)
          acc[i][j] = __builtin_amdgcn_mfma_f32_16x16x32_bf16(af[i], bfg[j], acc[i][j], 0, 0, 0);
    }
    __syncthreads();
  }

  // ---- epilogue ----
  if (n0 < 512) {
    // q: phi + row-major bf16 to Cout (q_b), stride 512
    short* scr = (short*)lds;   // 256x128
#pragma unroll
    for (int j = 0; j < 4; ++j) {
      const int col = wn * 64 + j * 16 + fr;
      const float bv = bias[n0 + col];
#pragma unroll
      for (int i = 0; i < 4; ++i) {
        const int row = wm * 64 + i * 16 + fq * 4;
#pragma unroll
        for (int r = 0; r < 4; ++r) {
          float v = acc[i][j][r] + bv;
          v = (v > 0.f) ? (v + 1.f) : __expf(v);   // phi = elu+1
          scr[(row + r) * 128 + col] = f2bf(v);
        }
      }
    }
    __syncthreads();
#pragma unroll
    for (int p = 0; p < 8; ++p) {
      const int off = p * 8192 + tid * 16;          // bytes
      const int row = off >> 8, colb = off & 255;   // 256B per row
      s16x8 v = *(const s16x8*)(lds + off);
      *(s16x8*)((short*)Cout + (size_t)(m0 + row) * 512 + n0 + (colb >> 1)) = v;
    }
  } else {
    // k/v: (phi for k) + per-head transposed write via scr_t[col][l]
    const bool do_phi = (n0 < 1024);
    short* tdst = do_phi ? ktb : vtb;
    const int f0 = n0 - (do_phi ? 512 : 1024);
#pragma unroll
    for (int j = 0; j < 4; ++j) {
      const int col = wn * 64 + j * 16 + fr;
      const float bv = bias[n0 + col];
      const int cx = col & 31;
#pragma unroll
      for (int i = 0; i < 4; ++i) {
        const int l = wm * 64 + i * 16 + fq * 4;
        s16x4 pk;
#pragma unroll
        for (int r = 0; r < 4; ++r) {
          float v = acc[i][j][r] + bv;
          if (do_phi) v = (v > 0.f) ? (v + 1.f) : __expf(v);
          pk[r] = f2bf(v);
        }
        *(s16x4*)(lds + col * 512 + (((l >> 3) ^ cx) * 16) + (l & 7) * 2) = pk;
      }
    }
    __syncthreads();
#pragma unroll
    for (int p = 0; p < 8; ++p) {
      const int g = p * 512 + tid;
      const int col = g >> 5, up = g & 31;
      const int u = up ^ (col & 31);
      s16x8 v = *(const s16x8*)(lds + col * 512 + up * 16);
      const int f = f0 + col;
      const int hb = ((m0 >> 13) << 3) + (f >> 6);
      short* dst = tdst + ((size_t)hb * 64 + (f & 63)) * 8192 + (m0 & 8191) + u * 8;
      *(s16x8*)dst = v;
    }
  }
}

// ---------------- kv partials via MFMA ----------------
__global__ __launch_bounds__(256, 4)
void kv_mfma(const short* __restrict__ kt, const short* __restrict__ vt,
             float* __restrict__ pkv, float* __restrict__ pks)
{
  const int hb = blockIdx.x, c = blockIdx.y;
  const int tid = threadIdx.x, wv = tid >> 6, lane = tid & 63;
  const int fr = lane & 15, fq = lane >> 4;
  const size_t base = (size_t)hb * 64 * 8192;
  const int l0 = c * 512;
  const short* vrow = vt + base + (size_t)fr * 8192 + l0 + fq * 8;
  const short* krow = kt + base + (size_t)(wv * 16 + fr) * 8192 + l0 + fq * 8;

  s16x8 ones;
#pragma unroll
  for (int j = 0; j < 8; ++j) ones[j] = (short)0x3F80;   // bf16 1.0

  f32x4 acc[4] = {};
  f32x4 accd = {};
#pragma unroll
  for (int ks = 0; ks < 16; ++ks) {
    s16x8 bfr = *(const s16x8*)(krow + ks * 32);
    accd = __builtin_amdgcn_mfma_f32_16x16x32_bf16(ones, bfr, accd, 0, 0, 0);
#pragma unroll
    for (int i = 0; i < 4; ++i) {
      s16x8 af = *(const s16x8*)(vrow + (size_t)(i * 16) * 8192 + ks * 32);
      acc[i] = __builtin_amdgcn_mfma_f32_16x16x32_bf16(af, bfr, acc[i], 0, 0, 0);
    }
  }
  float* o = pkv + ((size_t)hb * CH + c) * 4096;
#pragma unroll
  for (int i = 0; i < 4; ++i)
#pragma unroll
    for (int r = 0; r < 4; ++r)
      o[(i * 16 + fq * 4 + r) * 64 + wv * 16 + fr] = acc[i][r];
  if (fq == 0)
    pks[((size_t)hb * CH + c) * 64 + wv * 16 + fr] = accd[0];
}

// reduce partials -> bf16 kv_b [head][m][d], bf16 ksum_b [head][d] (with +1e-6)
__global__ void kv_reduce(const float* __restrict__ pkv, const float* __restrict__ pks,
                          short* __restrict__ kv_b, short* __restrict__ ksum_b)
{
  const int idx = blockIdx.x * 256 + threadIdx.x;   // head*4096 + m*64 + d
  const int head = idx >> 12, md = idx & 4095;
  float s = 0.f;
  for (int i = 0; i < CH; ++i) s += pkv[((size_t)head * CH + i) * 4096 + md];
  kv_b[idx] = f2bf(s);
  if (md < 64) {
    float t = 0.f;
    for (int i = 0; i < CH; ++i) t += pks[((size_t)head * CH + i) * 64 + md];
    ksum_b[head * 64 + md] = f2bf(t + 1e-6f);
  }
}

// ---------------- fused attn + output GEMM ----------------
// Per block: 64 rows, 256 threads (4 waves), LDS 72KB -> 2 blocks/CU.
// Loop over 8 heads as K-chunks:
//   - issue gload_lds staging of Ws = wo_t[512][k-chunk 64] (r6 unit swizzle)
//   - phase A: wave w computes attn rows w*16..+15 for head h (attn_mfma's
//     proven pattern, direct-global q/kv frags) -> At[64][64] LDS (swizzled)
//   - barrier (drains staging), phase B: acc += At @ Ws^T, frags from LDS
//   - barrier
// Epilogue: bias + 2x 32-row fp32 passes through LDS, coalesced stores.
__global__ __launch_bounds__(256, 2)
void attn_out(const short* __restrict__ q_b, const short* __restrict__ kv_b,
              const short* __restrict__ ksum_b, const short* __restrict__ wo_t,
              const float* __restrict__ b_out, float* __restrict__ out)
{
  __shared__ __align__(16) char lds[73728];   // At 8KB @0 | Ws 64KB @8192
  const int tid = threadIdx.x;
  const int wv = tid >> 6, lane = tid & 63;
  const int fr = lane & 15, fq = lane >> 4;
  const int l0 = blockIdx.x * 64;
  const int bb = l0 >> 13;                    // batch index

  // Ws staging: rows i*32 + (tid>>3); LDS unit tid&7 holds global unit (tid&7)^(row&7)
  const int srow = tid >> 3;
  const int sunit = (tid & 7) ^ (srow & 7);
  const short* Wg = wo_t + (size_t)srow * 512 + sunit * 8;
  char* ldsw = lds + 8192 + wv * 1024;        // + lane*16 implicit in gload_lds

  f32x4 acc[4][8] = {};

  for (int h = 0; h < 8; ++h) {
    // stage Ws chunk (fire-and-forget; consumed after the barrier)
#pragma unroll
    for (int i = 0; i < 16; ++i)
      gload16(Wg + (size_t)(i * 32) * 512 + h * 64, ldsw + i * 4096);

    // ---- phase A: attn for head h, this wave's 16-row slab ----
    {
      const int hb = bb * 8 + h;
      const short* kvp = kv_b + (size_t)hb * 4096;
      const short* ksp = ksum_b + hb * 64;
      const short* qb = q_b + (size_t)(l0 + wv * 16) * 512 + h * 64;
      f32x4 accn[4] = {};
      f32x4 accd = {};
#pragma unroll
      for (int kk = 0; kk < 2; ++kk) {
        s16x8 a = *(const s16x8*)(qb + (size_t)fr * 512 + kk * 32 + fq * 8);
        s16x8 bden = *(const s16x8*)(ksp + kk * 32 + fq * 8);
        accd = __builtin_amdgcn_mfma_f32_16x16x32_bf16(a, bden, accd, 0, 0, 0);
#pragma unroll
        for (int j = 0; j < 4; ++j) {
          s16x8 bfr = *(const s16x8*)(kvp + (j * 16 + fr) * 64 + kk * 32 + fq * 8);
          accn[j] = __builtin_amdgcn_mfma_f32_16x16x32_bf16(a, bfr, accn[j], 0, 0, 0);
        }
      }
      // write At[64][64] bf16 (row stride 128B, unit swizzle ^(row&7))
#pragma unroll
      for (int r = 0; r < 4; ++r) {
        const int row = wv * 16 + fq * 4 + r;
        const float dinv = 1.0f / accd[r];
#pragma unroll
        for (int j = 0; j < 4; ++j) {
          const int col = j * 16 + fr;
          *(short*)(lds + row * 128 + (((col >> 3) ^ (row & 7)) << 4) + ((col & 7) << 1))
              = f2bf(accn[j][r] * dinv);
        }
      }
    }
    __syncthreads();   // At ready + Ws landed

    // ---- phase B: acc += At @ Ws^T over this chunk's K=64 ----
#pragma unroll
    for (int kk = 0; kk < 2; ++kk) {
      s16x8 af[4];
#pragma unroll
      for (int i = 0; i < 4; ++i) {
        const int row = i * 16 + fr;
        const int u = (kk * 4 + fq) ^ (row & 7);
        af[i] = *(const s16x8*)(lds + row * 128 + u * 16);
      }
#pragma unroll
      for (int j = 0; j < 8; ++j) {
        const int n = wv * 128 + j * 16 + fr;
        const int u = (kk * 4 + fq) ^ (n & 7);
        s16x8 bw = *(const s16x8*)(lds + 8192 + n * 128 + u * 16);
#pragma unroll
        for (int i = 0; i < 4; ++i)
          acc[i][j] = __builtin_amdgcn_mfma_f32_16x16x32_bf16(af[i], bw, acc[i][j], 0, 0, 0);
      }
    }
    __syncthreads();   // protect At/Ws for next chunk
  }

  // ---- epilogue: 2 passes of 32 rows through 64KB fp32 scratch ----
  float* scrf = (float*)lds;
#pragma unroll
  for (int p = 0; p < 2; ++p) {
#pragma unroll
    for (int ii = 0; ii < 2; ++ii) {
      const int i = 2 * p + ii;
#pragma unroll
      for (int j = 0; j < 8; ++j) {
        const int col = wv * 128 + j * 16 + fr;
        const float bv = b_out[col];
#pragma unroll
        for (int r = 0; r < 4; ++r)
          scrf[(ii * 16 + fq * 4 + r) * 512 + col] = acc[i][j][r] + bv;
      }
    }
    __syncthreads();
#pragma unroll
    for (int pp = 0; pp < 16; ++pp) {
      const int off = pp * 4096 + tid * 16;
      const int row = off >> 11, colb = off & 2047;   // 2KB per row (512 fp32)
      float4 v = *(const float4*)(lds + off);
      *(float4*)(out + (size_t)(l0 + p * 32 + row) * 512 + (colb >> 2)) = v;
    }
    __syncthreads();
  }
}

// ---------------- launch ----------------
extern "C" void kernel_launch(void* const* d_in, const int* in_sizes, int n_in,
                              void* d_out, int out_size, void* d_ws, size_t ws_size,
                              hipStream_t stream)
{
  const float* x     = (const float*)d_in[0];
  const float* w_qkv = (const float*)d_in[1];
  const float* b_qkv = (const float*)d_in[2];
  const float* w_out = (const float*)d_in[3];
  const float* b_out = (const float*)d_in[4];

  char* ws = (char*)d_ws;
  size_t off = 0;
  short* x_b   = (short*)(ws + off); off += (size_t)MM * DD * 2;        // 32 MB
  short* wq_t  = (short*)(ws + off); off += (size_t)NQKV * DD * 2;      // 1.5 MB
  short* wo_t  = (short*)(ws + off); off += (size_t)DD * DD * 2;        // 0.5 MB
  short* q_b   = (short*)(ws + off); off += (size_t)MM * DD * 2;        // 32 MB
  short* kt    = (short*)(ws + off); off += (size_t)32 * 64 * LL * 2;   // 32 MB
  short* vt    = (short*)(ws + off); off += (size_t)32 * 64 * LL * 2;   // 32 MB
  float* pkv   = (float*)(ws + off); off += (size_t)32 * CH * 4096 * 4; // 8 MB
  float* pks   = (float*)(ws + off); off += (size_t)32 * CH * 64 * 4;   // 0.13 MB
  short* kv_b  = (short*)(ws + off); off += (size_t)32 * 4096 * 2;      // 0.25 MB
  short* ksum_b= (short*)(ws + off); off += (size_t)32 * 64 * 2;        // 4 KB

  conv_bf16<<<dim3(MM * DD / 8 / 256), dim3(256), 0, stream>>>(x, x_b, MM * DD);
  conv_wt<<<dim3((DD * NQKV + 255) / 256), dim3(256), 0, stream>>>(w_qkv, wq_t, DD, NQKV);
  conv_wt<<<dim3((DD * DD + 255) / 256), dim3(256), 0, stream>>>(w_out, wo_t, DD, DD);

  // qkv GEMM: q -> q_b (phi), k -> kt (phi, transposed), v -> vt (transposed)
  gemm_bt<<<dim3(MM / 256, NQKV / 128), dim3(512), 0, stream>>>(
      x_b, wq_t, b_qkv, (void*)q_b, kt, vt);

  kv_mfma<<<dim3(32, CH), dim3(256), 0, stream>>>(kt, vt, pkv, pks);
  kv_reduce<<<dim3(512), dim3(256), 0, stream>>>(pkv, pks, kv_b, ksum_b);

  // fused attn + output GEMM -> d_out
  attn_out<<<dim3(MM / 64), dim3(256), 0, stream>>>(
      q_b, kv_b, ksum_b, wo_t, b_out, (float*)d_out);
}